// Round 5
// baseline (712.376 us; speedup 1.0000x reference)
//
#include <hip/hip_runtime.h>

typedef __attribute__((ext_vector_type(8))) short bfrag8;   // 8 bf16 in 4 VGPRs
typedef __attribute__((ext_vector_type(4))) float facc4;    // 4 fp32 acc

#define BROWS 64    // rows per bucket == one wave (deterministic intra-wave scan)

static __device__ __forceinline__ float bf2f(ushort u) {
    union { unsigned int i; float f; } x;
    x.i = ((unsigned int)u) << 16;
    return x.f;
}
static __device__ __forceinline__ ushort f2bf(float f) {
    union { float f; unsigned int i; } x;
    x.f = f;
    unsigned int r = x.i + 0x7FFFu + ((x.i >> 16) & 1u);   // RNE
    return (ushort)(r >> 16);
}

// ---------------- preprocessing ----------------

__global__ void k_count(const int* __restrict__ row, int E, int* __restrict__ cnt) {
    int e = blockIdx.x * blockDim.x + threadIdx.x;
    if (e < E) atomicAdd(&cnt[row[e]], 1);
}

// per-bucket (64-row) degree sums: one wave per bucket
__global__ void k_bsum(const int* __restrict__ cnt, int* __restrict__ bsum,
                       int nb, int N) {
    int w = (blockIdx.x * blockDim.x + threadIdx.x) >> 6;
    int lane = threadIdx.x & 63;
    if (w < nb) {
        int i = w * BROWS + lane;
        int v = (i < N) ? cnt[i] : 0;
        #pragma unroll
        for (int off = 32; off > 0; off >>= 1) v += __shfl_xor(v, off);
        if (lane == 0) bsum[w] = v;
    }
}

// single-block exclusive scan of bucket sums -> monotone bbase[0..nb] (bbase[nb]=E)
__global__ void k_bscan(const int* __restrict__ bsum, int* __restrict__ bbase,
                        int* __restrict__ bcur, int nb) {
    __shared__ int tmp[256];
    __shared__ int carry;
    if (threadIdx.x == 0) carry = 0;
    __syncthreads();
    for (int base = 0; base < nb; base += 256) {
        int i = base + threadIdx.x;
        int v = (i < nb) ? bsum[i] : 0;
        tmp[threadIdx.x] = v;
        __syncthreads();
        #pragma unroll
        for (int off = 1; off < 256; off <<= 1) {
            int t = (threadIdx.x >= off) ? tmp[threadIdx.x - off] : 0;
            __syncthreads();
            tmp[threadIdx.x] += t;
            __syncthreads();
        }
        int excl = tmp[threadIdx.x] - v;
        if (i < nb) {
            bbase[i] = carry + excl;
            bcur[i]  = carry + excl;
        }
        __syncthreads();
        if (threadIdx.x == 255) carry += tmp[255];
        __syncthreads();
    }
    if (threadIdx.x == 0) bbase[nb] = carry;
}

// per-row CSR offsets: one wave per bucket, deterministic intra-wave scan + bbase
__global__ void k_alloc2(const int* __restrict__ cnt, const int* __restrict__ bbase,
                         int* __restrict__ rptr, float* __restrict__ dinv,
                         int nb, int N) {
    int w = (blockIdx.x * blockDim.x + threadIdx.x) >> 6;
    int lane = threadIdx.x & 63;
    if (w >= nb) return;
    int i = w * BROWS + lane;
    int c = (i < N) ? cnt[i] : 0;
    int v = c;
    #pragma unroll
    for (int off = 1; off < 64; off <<= 1) {
        int n = __shfl_up(v, off);
        if (lane >= off) v += n;
    }
    if (i < N) {
        rptr[i] = bbase[w] + v - c;          // monotone: bbase monotone + lane-monotone scan
        dinv[i] = rsqrtf((float)(c + 1));    // +1 self-loop
    }
}

// phase 1: bin edges by 64-row bucket; appends are line-local per bucket
__global__ void k_bscatter(const int* __restrict__ row, const int* __restrict__ col, int E,
                           int* __restrict__ bcur, int2* __restrict__ bkt) {
    int e = blockIdx.x * blockDim.x + threadIdx.x;
    if (e < E) {
        int r = row[e];
        int p = atomicAdd(&bcur[r >> 6], 1);
        bkt[p] = make_int2(r, col[e]);
    }
}

// phase 2: one block per bucket; LDS cursors; cidx writes confined to a ~4KB window
__global__ void k_place(const int2* __restrict__ bkt, const int* __restrict__ rptr,
                        const int* __restrict__ bbase,
                        int* __restrict__ cidx, int N) {
    __shared__ int cur[BROWS];
    int b = blockIdx.x;
    int lo = b * BROWS;
    int hi = min(lo + BROWS, N);
    if (threadIdx.x < hi - lo) cur[threadIdx.x] = rptr[lo + threadIdx.x];
    __syncthreads();
    int start = bbase[b];
    int end = bbase[b + 1];
    for (int idx = start + threadIdx.x; idx < end; idx += blockDim.x) {
        int2 rc = bkt[idx];
        int p = atomicAdd(&cur[rc.x - lo], 1);
        cidx[p] = rc.y;
    }
}

// ---------------- fp32 -> bf16 convert (for x) ----------------
__global__ void k_cvt(const float* __restrict__ in, ushort* __restrict__ out, int n4) {
    int i = blockIdx.x * blockDim.x + threadIdx.x;
    if (i < n4) {
        float4 v = ((const float4*)in)[i];
        ushort4 o;
        o.x = f2bf(v.x); o.y = f2bf(v.y); o.z = f2bf(v.z); o.w = f2bf(v.w);
        ((ushort4*)out)[i] = o;
    }
}

// ---------------- MFMA GEMM: T[N,64] = H[N,64] @ W[64,64] ----------------
__global__ void k_gemm(const ushort* __restrict__ H, const float* __restrict__ W,
                       ushort* __restrict__ T, int ntiles, int N) {
    int lane = threadIdx.x & 63;
    int wid = (blockIdx.x * blockDim.x + threadIdx.x) >> 6;
    int nw = (gridDim.x * blockDim.x) >> 6;
    int m = lane & 15, quad = lane >> 4;

    bfrag8 bf[2][4];   // all of W in B-frags, loaded once
    #pragma unroll
    for (int s = 0; s < 2; s++)
        #pragma unroll
        for (int c = 0; c < 4; c++) {
            bfrag8 f;
            #pragma unroll
            for (int j = 0; j < 8; j++) {
                int k = 32 * s + quad * 8 + j;
                f[j] = (short)f2bf(W[k * 64 + 16 * c + m]);
            }
            bf[s][c] = f;
        }

    for (int t = wid; t < ntiles; t += nw) {
        int nodeA = t * 16 + m;
        if (nodeA >= N) nodeA = N - 1;
        const ushort* arow = H + (size_t)nodeA * 64;
        bfrag8 a0 = *(const bfrag8*)(arow + quad * 8);
        bfrag8 a1 = *(const bfrag8*)(arow + 32 + quad * 8);
        facc4 acc[4];
        #pragma unroll
        for (int c = 0; c < 4; c++) { acc[c][0]=0.f; acc[c][1]=0.f; acc[c][2]=0.f; acc[c][3]=0.f; }
        #pragma unroll
        for (int c = 0; c < 4; c++) {
            acc[c] = __builtin_amdgcn_mfma_f32_16x16x32_bf16(a0, bf[0][c], acc[c], 0, 0, 0);
            acc[c] = __builtin_amdgcn_mfma_f32_16x16x32_bf16(a1, bf[1][c], acc[c], 0, 0, 0);
        }
        #pragma unroll
        for (int c = 0; c < 4; c++)
            #pragma unroll
            for (int r = 0; r < 4; r++) {
                int node = t * 16 + quad * 4 + r;
                if (node < N) T[(size_t)node * 64 + c * 16 + m] = f2bf(acc[c][r]);
            }
    }
}

// ---------------- fused propagate + bias + BN + ReLU ----------------
// 16-wide gather unroll for MLP (agg is latency-bound: 19% HBM, 18% VALU at 8-wide).
__global__ void k_agg(const ushort* __restrict__ T, const int* __restrict__ rptr,
                      const int* __restrict__ cnt, const float* __restrict__ dinv,
                      const int* __restrict__ cidx,
                      const float* __restrict__ bias, const float* __restrict__ g,
                      const float* __restrict__ be, const float* __restrict__ mm,
                      const float* __restrict__ vv, int do_bn,
                      float* __restrict__ outf, ushort* __restrict__ outb, int N) {
    int lane = threadIdx.x & 63;
    int wid = (blockIdx.x * blockDim.x + threadIdx.x) >> 6;
    int nw = (gridDim.x * blockDim.x) >> 6;

    float bval = bias[lane];
    float sc = 1.f, sh = 0.f;
    if (do_bn) {
        sc = g[lane] * rsqrtf(vv[lane] + 1e-5f);
        sh = be[lane] - mm[lane] * sc;
    }

    for (int r = wid; r < N; r += nw) {
        int start = rptr[r];
        int e = cnt[r];
        float a0 = 0.f, a1 = 0.f, a2 = 0.f, a3 = 0.f;
        int i = 0;
        for (; i + 16 <= e; i += 16) {
            int cc[16];
            #pragma unroll
            for (int j = 0; j < 16; j++) cc[j] = cidx[start + i + j];
            float ww[16];
            #pragma unroll
            for (int j = 0; j < 16; j++) ww[j] = dinv[cc[j]];
            float tt[16];
            #pragma unroll
            for (int j = 0; j < 16; j++) tt[j] = bf2f(T[(size_t)cc[j] * 64 + lane]);
            #pragma unroll
            for (int j = 0; j < 16; j += 4) {
                a0 = fmaf(ww[j + 0], tt[j + 0], a0);
                a1 = fmaf(ww[j + 1], tt[j + 1], a1);
                a2 = fmaf(ww[j + 2], tt[j + 2], a2);
                a3 = fmaf(ww[j + 3], tt[j + 3], a3);
            }
        }
        for (; i + 4 <= e; i += 4) {
            int cc[4];
            #pragma unroll
            for (int j = 0; j < 4; j++) cc[j] = cidx[start + i + j];
            float ww[4];
            #pragma unroll
            for (int j = 0; j < 4; j++) ww[j] = dinv[cc[j]];
            float tt[4];
            #pragma unroll
            for (int j = 0; j < 4; j++) tt[j] = bf2f(T[(size_t)cc[j] * 64 + lane]);
            a0 = fmaf(ww[0], tt[0], a0);
            a1 = fmaf(ww[1], tt[1], a1);
            a2 = fmaf(ww[2], tt[2], a2);
            a3 = fmaf(ww[3], tt[3], a3);
        }
        for (; i < e; i++) {
            int c = cidx[start + i];
            a0 = fmaf(dinv[c], bf2f(T[(size_t)c * 64 + lane]), a0);
        }
        float dr = dinv[r];
        float val = dr * (((a0 + a1) + (a2 + a3)) + dr * bf2f(T[(size_t)r * 64 + lane])) + bval;
        if (do_bn) val = fmaxf(val * sc + sh, 0.f);
        if (outf) outf[(size_t)r * 64 + lane] = val;
        if (outb) outb[(size_t)r * 64 + lane] = f2bf(val);
    }
}

// ---------------- launcher ----------------

extern "C" void kernel_launch(void* const* d_in, const int* in_sizes, int n_in,
                              void* d_out, int out_size, void* d_ws, size_t ws_size,
                              hipStream_t stream) {
    const float* x  = (const float*)d_in[0];
    const int*   ei = (const int*)d_in[1];
    const float *W1 = (const float*)d_in[2],  *b1 = (const float*)d_in[3];
    const float *g1 = (const float*)d_in[4],  *be1= (const float*)d_in[5];
    const float *m1 = (const float*)d_in[6],  *v1 = (const float*)d_in[7];
    const float *W2 = (const float*)d_in[8],  *b2 = (const float*)d_in[9];
    const float *g2 = (const float*)d_in[10], *be2= (const float*)d_in[11];
    const float *m2 = (const float*)d_in[12], *v2 = (const float*)d_in[13];
    const float *W3 = (const float*)d_in[14], *b3 = (const float*)d_in[15];

    int N = in_sizes[0] / 64;
    int E = in_sizes[1] / 2;
    const int* row = ei;
    const int* col = ei + E;
    int nb = (N + BROWS - 1) / BROWS;

    char* p = (char*)d_ws;
    auto take = [&](size_t b) -> char* {
        char* q = p;
        p += (b + 255) & ~(size_t)255;
        return q;
    };
    int*    cnt   = (int*)   take((size_t)N * 4);
    int*    rptr  = (int*)   take((size_t)N * 4);
    float*  dinv  = (float*) take((size_t)N * 4);
    int*    bsum  = (int*)   take((size_t)nb * 4);
    int*    bbase = (int*)   take((size_t)(nb + 1) * 4);
    int*    bcur  = (int*)   take((size_t)nb * 4);
    int*    cidx  = (int*)   take((size_t)E * 4);
    int2*   bkt   = (int2*)  take((size_t)E * 8);
    ushort* xb    = (ushort*)take((size_t)N * 64 * 2);
    ushort* t     = (ushort*)take((size_t)N * 64 * 2);
    ushort* h     = (ushort*)take((size_t)N * 64 * 2);

    hipMemsetAsync(cnt, 0, (size_t)N * 4, stream);

    const int TB = 256;
    int wave_blocks = (nb * 64 + TB - 1) / TB;
    k_count   <<<(E + TB - 1) / TB, TB, 0, stream>>>(row, E, cnt);
    k_bsum    <<<wave_blocks, TB, 0, stream>>>(cnt, bsum, nb, N);
    k_bscan   <<<1, TB, 0, stream>>>(bsum, bbase, bcur, nb);
    k_alloc2  <<<wave_blocks, TB, 0, stream>>>(cnt, bbase, rptr, dinv, nb, N);
    k_bscatter<<<(E + TB - 1) / TB, TB, 0, stream>>>(row, col, E, bcur, bkt);
    k_place   <<<nb, TB, 0, stream>>>(bkt, rptr, bbase, cidx, N);

    int n4 = N * 64 / 4;
    k_cvt<<<(n4 + TB - 1) / TB, TB, 0, stream>>>(x, xb, n4);

    float* outp = (float*)d_out;   // [0, N*64): embeddings fp32; [N*64, 2N*64): preds
    int ntiles = (N + 15) >> 4;
    const int GG = 512;    // gemm blocks
    const int GA = 2048;   // agg blocks -> 8192 waves

    // layer 1
    k_gemm<<<GG, TB, 0, stream>>>(xb, W1, t, ntiles, N);
    k_agg <<<GA, TB, 0, stream>>>(t, rptr, cnt, dinv, cidx, b1, g1, be1, m1, v1, 1,
                                  (float*)nullptr, h, N);
    // layer 2 -> embeddings (fp32 to d_out) + bf16 h for layer 3
    k_gemm<<<GG, TB, 0, stream>>>(h, W2, t, ntiles, N);
    k_agg <<<GA, TB, 0, stream>>>(t, rptr, cnt, dinv, cidx, b2, g2, be2, m2, v2, 1,
                                  outp, h, N);
    // layer 3 -> predictions
    k_gemm<<<GG, TB, 0, stream>>>(h, W3, t, ntiles, N);
    k_agg <<<GA, TB, 0, stream>>>(t, rptr, cnt, dinv, cidx, b3, b3, b3, b3, b3, 0,
                                  outp + (size_t)N * 64, (ushort*)nullptr, N);
}

// Round 6
// 555.289 us; speedup vs baseline: 1.2829x; 1.2829x over previous
//
#include <hip/hip_runtime.h>

typedef __attribute__((ext_vector_type(8))) short bfrag8;   // 8 bf16 in 4 VGPRs
typedef __attribute__((ext_vector_type(4))) float facc4;    // 4 fp32 acc

#define BROWS 64    // rows per scan-bucket == one wave (deterministic intra-wave scan)
#define BR2   8     // rows per scatter-bucket (12.5K cursors: no atomic contention,
                    // line-local appends). Record packs rl(3b)<<27 | col(17b).

static __device__ __forceinline__ float bf2f(ushort u) {
    union { unsigned int i; float f; } x;
    x.i = ((unsigned int)u) << 16;
    return x.f;
}
static __device__ __forceinline__ ushort f2bf(float f) {
    union { float f; unsigned int i; } x;
    x.f = f;
    unsigned int r = x.i + 0x7FFFu + ((x.i >> 16) & 1u);   // RNE
    return (ushort)(r >> 16);
}

// ---------------- preprocessing ----------------

__global__ void k_count(const int* __restrict__ row, int E, int* __restrict__ cnt) {
    int e = blockIdx.x * blockDim.x + threadIdx.x;
    if (e < E) atomicAdd(&cnt[row[e]], 1);
}

// per-bucket (64-row) degree sums: one wave per bucket
__global__ void k_bsum(const int* __restrict__ cnt, int* __restrict__ bsum,
                       int nb, int N) {
    int w = (blockIdx.x * blockDim.x + threadIdx.x) >> 6;
    int lane = threadIdx.x & 63;
    if (w < nb) {
        int i = w * BROWS + lane;
        int v = (i < N) ? cnt[i] : 0;
        #pragma unroll
        for (int off = 32; off > 0; off >>= 1) v += __shfl_xor(v, off);
        if (lane == 0) bsum[w] = v;
    }
}

// single-block exclusive scan of bucket sums -> monotone bbase[0..nb]
__global__ void k_bscan(const int* __restrict__ bsum, int* __restrict__ bbase, int nb) {
    __shared__ int tmp[256];
    __shared__ int carry;
    if (threadIdx.x == 0) carry = 0;
    __syncthreads();
    for (int base = 0; base < nb; base += 256) {
        int i = base + threadIdx.x;
        int v = (i < nb) ? bsum[i] : 0;
        tmp[threadIdx.x] = v;
        __syncthreads();
        #pragma unroll
        for (int off = 1; off < 256; off <<= 1) {
            int t = (threadIdx.x >= off) ? tmp[threadIdx.x - off] : 0;
            __syncthreads();
            tmp[threadIdx.x] += t;
            __syncthreads();
        }
        int excl = tmp[threadIdx.x] - v;
        if (i < nb) bbase[i] = carry + excl;
        __syncthreads();
        if (threadIdx.x == 255) carry += tmp[255];
        __syncthreads();
    }
    if (threadIdx.x == 0) bbase[nb] = carry;
}

// per-row CSR offsets: one wave per 64-row bucket, deterministic scan + bbase
__global__ void k_alloc2(const int* __restrict__ cnt, const int* __restrict__ bbase,
                         int* __restrict__ rptr, float* __restrict__ dinv,
                         int nb, int N) {
    int w = (blockIdx.x * blockDim.x + threadIdx.x) >> 6;
    int lane = threadIdx.x & 63;
    if (w >= nb) return;
    int i = w * BROWS + lane;
    int c = (i < N) ? cnt[i] : 0;
    int v = c;
    #pragma unroll
    for (int off = 1; off < 64; off <<= 1) {
        int n = __shfl_up(v, off);
        if (lane >= off) v += n;
    }
    if (i < N) {
        rptr[i] = bbase[w] + v - c;          // monotone
        dinv[i] = rsqrtf((float)(c + 1));    // +1 self-loop
    }
}

// 8-row scatter-bucket cursors start at rptr[8b]
__global__ void k_binit8(const int* __restrict__ rptr, int* __restrict__ bcur8,
                         int nb8, int N) {
    int b = blockIdx.x * blockDim.x + threadIdx.x;
    if (b < nb8) bcur8[b] = rptr[min(b * BR2, N - 1)];
}

// phase 1: bin edges into 8-row buckets; 12.5K cursors -> low contention;
// single-int records keep appends line-local.
__global__ void k_bscatter(const int* __restrict__ row, const int* __restrict__ col, int E,
                           int* __restrict__ bcur8, int* __restrict__ bkt) {
    int e = blockIdx.x * blockDim.x + threadIdx.x;
    if (e < E) {
        int r = row[e];
        int p = atomicAdd(&bcur8[r / BR2], 1);
        bkt[p] = ((r & (BR2 - 1)) << 27) | col[e];
    }
}

// phase 2: one wave per 8-row bucket; LDS cursors; reads/writes 512B windows
__global__ void k_place8(const int* __restrict__ bkt, const int* __restrict__ rptr,
                         int* __restrict__ cidx, int N, int E) {
    __shared__ int cur[BR2];
    int b = blockIdx.x;
    int lo = b * BR2;
    int hi = min(lo + BR2, N);
    if (threadIdx.x < hi - lo) cur[threadIdx.x] = rptr[lo + threadIdx.x];
    __syncthreads();
    int start = rptr[lo];
    int end = (hi < N) ? rptr[hi] : E;
    for (int idx = start + threadIdx.x; idx < end; idx += blockDim.x) {
        int v = bkt[idx];
        int p = atomicAdd(&cur[v >> 27], 1);
        cidx[p] = v & 0x07FFFFFF;
    }
}

// ---------------- MFMA GEMM: T[N,64] = H[N,64] @ W[64,64] ----------------
// FP32IN: read A rows as fp32 (layer 1 input x) and convert on the fly.
template <bool FP32IN>
__global__ void k_gemm(const void* __restrict__ Hv, const float* __restrict__ W,
                       ushort* __restrict__ T, int ntiles, int N) {
    int lane = threadIdx.x & 63;
    int wid = (blockIdx.x * blockDim.x + threadIdx.x) >> 6;
    int nw = (gridDim.x * blockDim.x) >> 6;
    int m = lane & 15, quad = lane >> 4;

    bfrag8 bf[2][4];   // all of W in B-frags, loaded once
    #pragma unroll
    for (int s = 0; s < 2; s++)
        #pragma unroll
        for (int c = 0; c < 4; c++) {
            bfrag8 f;
            #pragma unroll
            for (int j = 0; j < 8; j++) {
                int k = 32 * s + quad * 8 + j;
                f[j] = (short)f2bf(W[k * 64 + 16 * c + m]);
            }
            bf[s][c] = f;
        }

    for (int t = wid; t < ntiles; t += nw) {
        int nodeA = t * 16 + m;
        if (nodeA >= N) nodeA = N - 1;
        bfrag8 a0, a1;
        if (FP32IN) {
            const float* arow = (const float*)Hv + (size_t)nodeA * 64;
            #pragma unroll
            for (int s = 0; s < 2; s++) {
                float4 u0 = *(const float4*)(arow + s * 32 + quad * 8);
                float4 u1 = *(const float4*)(arow + s * 32 + quad * 8 + 4);
                bfrag8 f;
                f[0] = (short)f2bf(u0.x); f[1] = (short)f2bf(u0.y);
                f[2] = (short)f2bf(u0.z); f[3] = (short)f2bf(u0.w);
                f[4] = (short)f2bf(u1.x); f[5] = (short)f2bf(u1.y);
                f[6] = (short)f2bf(u1.z); f[7] = (short)f2bf(u1.w);
                if (s == 0) a0 = f; else a1 = f;
            }
        } else {
            const ushort* arow = (const ushort*)Hv + (size_t)nodeA * 64;
            a0 = *(const bfrag8*)(arow + quad * 8);
            a1 = *(const bfrag8*)(arow + 32 + quad * 8);
        }
        facc4 acc[4];
        #pragma unroll
        for (int c = 0; c < 4; c++) { acc[c][0]=0.f; acc[c][1]=0.f; acc[c][2]=0.f; acc[c][3]=0.f; }
        #pragma unroll
        for (int c = 0; c < 4; c++) {
            acc[c] = __builtin_amdgcn_mfma_f32_16x16x32_bf16(a0, bf[0][c], acc[c], 0, 0, 0);
            acc[c] = __builtin_amdgcn_mfma_f32_16x16x32_bf16(a1, bf[1][c], acc[c], 0, 0, 0);
        }
        #pragma unroll
        for (int c = 0; c < 4; c++)
            #pragma unroll
            for (int r = 0; r < 4; r++) {
                int node = t * 16 + quad * 4 + r;
                if (node < N) T[(size_t)node * 64 + c * 16 + m] = f2bf(acc[c][r]);
            }
    }
}

// ---------------- fused propagate + bias + BN + ReLU ----------------
__global__ void k_agg(const ushort* __restrict__ T, const int* __restrict__ rptr,
                      const int* __restrict__ cnt, const float* __restrict__ dinv,
                      const int* __restrict__ cidx,
                      const float* __restrict__ bias, const float* __restrict__ g,
                      const float* __restrict__ be, const float* __restrict__ mm,
                      const float* __restrict__ vv, int do_bn,
                      float* __restrict__ outf, ushort* __restrict__ outb, int N) {
    int lane = threadIdx.x & 63;
    int wid = (blockIdx.x * blockDim.x + threadIdx.x) >> 6;
    int nw = (gridDim.x * blockDim.x) >> 6;

    float bval = bias[lane];
    float sc = 1.f, sh = 0.f;
    if (do_bn) {
        sc = g[lane] * rsqrtf(vv[lane] + 1e-5f);
        sh = be[lane] - mm[lane] * sc;
    }

    for (int r = wid; r < N; r += nw) {
        int start = rptr[r];
        int e = cnt[r];
        float a0 = 0.f, a1 = 0.f, a2 = 0.f, a3 = 0.f;
        int i = 0;
        for (; i + 16 <= e; i += 16) {
            int cc[16];
            #pragma unroll
            for (int j = 0; j < 16; j++) cc[j] = cidx[start + i + j];
            float ww[16];
            #pragma unroll
            for (int j = 0; j < 16; j++) ww[j] = dinv[cc[j]];
            float tt[16];
            #pragma unroll
            for (int j = 0; j < 16; j++) tt[j] = bf2f(T[(size_t)cc[j] * 64 + lane]);
            #pragma unroll
            for (int j = 0; j < 16; j += 4) {
                a0 = fmaf(ww[j + 0], tt[j + 0], a0);
                a1 = fmaf(ww[j + 1], tt[j + 1], a1);
                a2 = fmaf(ww[j + 2], tt[j + 2], a2);
                a3 = fmaf(ww[j + 3], tt[j + 3], a3);
            }
        }
        for (; i + 4 <= e; i += 4) {
            int cc[4];
            #pragma unroll
            for (int j = 0; j < 4; j++) cc[j] = cidx[start + i + j];
            float ww[4];
            #pragma unroll
            for (int j = 0; j < 4; j++) ww[j] = dinv[cc[j]];
            float tt[4];
            #pragma unroll
            for (int j = 0; j < 4; j++) tt[j] = bf2f(T[(size_t)cc[j] * 64 + lane]);
            a0 = fmaf(ww[0], tt[0], a0);
            a1 = fmaf(ww[1], tt[1], a1);
            a2 = fmaf(ww[2], tt[2], a2);
            a3 = fmaf(ww[3], tt[3], a3);
        }
        for (; i < e; i++) {
            int c = cidx[start + i];
            a0 = fmaf(dinv[c], bf2f(T[(size_t)c * 64 + lane]), a0);
        }
        float dr = dinv[r];
        float val = dr * (((a0 + a1) + (a2 + a3)) + dr * bf2f(T[(size_t)r * 64 + lane])) + bval;
        if (do_bn) val = fmaxf(val * sc + sh, 0.f);
        if (outf) outf[(size_t)r * 64 + lane] = val;
        if (outb) outb[(size_t)r * 64 + lane] = f2bf(val);
    }
}

// ---------------- launcher ----------------

extern "C" void kernel_launch(void* const* d_in, const int* in_sizes, int n_in,
                              void* d_out, int out_size, void* d_ws, size_t ws_size,
                              hipStream_t stream) {
    const float* x  = (const float*)d_in[0];
    const int*   ei = (const int*)d_in[1];
    const float *W1 = (const float*)d_in[2],  *b1 = (const float*)d_in[3];
    const float *g1 = (const float*)d_in[4],  *be1= (const float*)d_in[5];
    const float *m1 = (const float*)d_in[6],  *v1 = (const float*)d_in[7];
    const float *W2 = (const float*)d_in[8],  *b2 = (const float*)d_in[9];
    const float *g2 = (const float*)d_in[10], *be2= (const float*)d_in[11];
    const float *m2 = (const float*)d_in[12], *v2 = (const float*)d_in[13];
    const float *W3 = (const float*)d_in[14], *b3 = (const float*)d_in[15];

    int N = in_sizes[0] / 64;
    int E = in_sizes[1] / 2;
    const int* row = ei;
    const int* col = ei + E;
    int nb  = (N + BROWS - 1) / BROWS;   // 64-row scan buckets
    int nb8 = (N + BR2 - 1) / BR2;       // 8-row scatter buckets

    char* p = (char*)d_ws;
    auto take = [&](size_t b) -> char* {
        char* q = p;
        p += (b + 255) & ~(size_t)255;
        return q;
    };
    int*    cnt   = (int*)   take((size_t)N * 4);
    int*    rptr  = (int*)   take((size_t)N * 4);
    float*  dinv  = (float*) take((size_t)N * 4);
    int*    bsum  = (int*)   take((size_t)nb * 4);
    int*    bbase = (int*)   take((size_t)(nb + 1) * 4);
    int*    bcur8 = (int*)   take((size_t)nb8 * 4);
    int*    cidx  = (int*)   take((size_t)E * 4);
    int*    bkt   = (int*)   take((size_t)E * 4);
    ushort* t     = (ushort*)take((size_t)N * 64 * 2);
    ushort* h     = (ushort*)take((size_t)N * 64 * 2);

    hipMemsetAsync(cnt, 0, (size_t)N * 4, stream);

    const int TB = 256;
    int wave_blocks = (nb * 64 + TB - 1) / TB;
    k_count   <<<(E + TB - 1) / TB, TB, 0, stream>>>(row, E, cnt);
    k_bsum    <<<wave_blocks, TB, 0, stream>>>(cnt, bsum, nb, N);
    k_bscan   <<<1, TB, 0, stream>>>(bsum, bbase, nb);
    k_alloc2  <<<wave_blocks, TB, 0, stream>>>(cnt, bbase, rptr, dinv, nb, N);
    k_binit8  <<<(nb8 + TB - 1) / TB, TB, 0, stream>>>(rptr, bcur8, nb8, N);
    k_bscatter<<<(E + TB - 1) / TB, TB, 0, stream>>>(row, col, E, bcur8, bkt);
    k_place8  <<<nb8, 64, 0, stream>>>(bkt, rptr, cidx, N, E);

    float* outp = (float*)d_out;   // [0, N*64): embeddings fp32; [N*64, 2N*64): preds
    int ntiles = (N + 15) >> 4;
    const int GG = 512;    // gemm blocks
    const int GA = 2048;   // agg blocks -> 8192 waves

    // layer 1 (fp32 x read directly, converted in-kernel)
    k_gemm<true> <<<GG, TB, 0, stream>>>(x, W1, t, ntiles, N);
    k_agg <<<GA, TB, 0, stream>>>(t, rptr, cnt, dinv, cidx, b1, g1, be1, m1, v1, 1,
                                  (float*)nullptr, h, N);
    // layer 2 -> embeddings (fp32 to d_out) + bf16 h for layer 3
    k_gemm<false><<<GG, TB, 0, stream>>>(h, W2, t, ntiles, N);
    k_agg <<<GA, TB, 0, stream>>>(t, rptr, cnt, dinv, cidx, b2, g2, be2, m2, v2, 1,
                                  outp, h, N);
    // layer 3 -> predictions
    k_gemm<false><<<GG, TB, 0, stream>>>(h, W3, t, ntiles, N);
    k_agg <<<GA, TB, 0, stream>>>(t, rptr, cnt, dinv, cidx, b3, b3, b3, b3, b3, 0,
                                  outp + (size_t)N * 64, (ushort*)nullptr, N);
}

// Round 7
// 428.376 us; speedup vs baseline: 1.6630x; 1.2963x over previous
//
#include <hip/hip_runtime.h>

typedef __attribute__((ext_vector_type(8))) short bfrag8;   // 8 bf16 in 4 VGPRs
typedef __attribute__((ext_vector_type(4))) float facc4;    // 4 fp32 acc

#define CROWS  512    // rows per coarse bucket (power of 2; rl fits 9 bits)
#define NCBMAX 256    // max coarse buckets (N <= 131072, also col 17-bit limit)
#define CAP    16384  // bkt region capacity per bucket (~2x expected load)
#define CHUNK  8192   // edges per k_part block

static __device__ __forceinline__ float bf2f(ushort u) {
    union { unsigned int i; float f; } x;
    x.i = ((unsigned int)u) << 16;
    return x.f;
}
static __device__ __forceinline__ ushort f2bf(float f) {
    union { float f; unsigned int i; } x;
    x.f = f;
    unsigned int r = x.i + 0x7FFFu + ((x.i >> 16) & 1u);   // RNE
    return (ushort)(r >> 16);
}

// ---------------- preprocessing: 2-phase partition, no global random atomics ----

__global__ void k_cinit(int* __restrict__ ccur, int ncb) {
    int b = blockIdx.x * blockDim.x + threadIdx.x;
    if (b < ncb) ccur[b] = b * CAP;
}

// phase 1: partition edges into coarse buckets. LDS staging: every bkt line is
// written by one block within a tight window -> low write amplification.
__global__ void k_part(const int* __restrict__ row, const int* __restrict__ col, int E,
                       int* __restrict__ ccur, int* __restrict__ bkt, int ncb) {
    __shared__ int recs[CHUNK];          // packed (rl<<17|col)
    __shared__ unsigned short cbl[CHUNK];
    __shared__ int hist[NCBMAX], lbase[NCBMAX], loff[NCBMAX];
    int tid = threadIdx.x;
    int chunk0 = blockIdx.x * CHUNK;
    for (int i = tid; i < ncb; i += blockDim.x) hist[i] = 0;
    __syncthreads();
    for (int j = tid; j < CHUNK; j += blockDim.x) {
        int e = chunk0 + j;
        if (e < E) {
            int r = row[e];
            int cb = r >> 9;
            recs[j] = ((r & (CROWS - 1)) << 17) | col[e];
            cbl[j] = (unsigned short)cb;
            atomicAdd(&hist[cb], 1);
        } else cbl[j] = 0xFFFF;
    }
    __syncthreads();
    for (int i = tid; i < ncb; i += blockDim.x) {
        int h = hist[i];
        lbase[i] = h ? atomicAdd(&ccur[i], h) : 0;
        loff[i] = 0;
    }
    __syncthreads();
    for (int j = tid; j < CHUNK; j += blockDim.x) {
        unsigned short cb = cbl[j];
        if (cb != 0xFFFF) {
            int p = lbase[cb] + atomicAdd(&loff[cb], 1);
            if (p < (cb + 1) * CAP) bkt[p] = recs[j];   // overflow guard (never hits)
        }
    }
}

// tiny scan of coarse-bucket counts -> cbase (tight cidx packing)
__global__ void k_scan(const int* __restrict__ ccur, int* __restrict__ cbase, int ncb) {
    __shared__ int tmp[NCBMAX];
    int tid = threadIdx.x;
    int v = (tid < ncb) ? min(ccur[tid] - tid * CAP, CAP) : 0;
    tmp[tid] = v;
    __syncthreads();
    #pragma unroll
    for (int off = 1; off < NCBMAX; off <<= 1) {
        int t = (tid >= off) ? tmp[tid - off] : 0;
        __syncthreads();
        tmp[tid] += t;
        __syncthreads();
    }
    if (tid < ncb) cbase[tid] = tmp[tid] - v;   // exclusive
    if (tid == ncb - 1) cbase[ncb] = tmp[tid];
}

// phase 2 (fused): per coarse bucket — row histogram -> dinv, deterministic LDS
// scan -> monotone rptr, LDS-cursor placement into a private contiguous window.
__global__ void k_build(const int* __restrict__ bkt, const int* __restrict__ ccur,
                        const int* __restrict__ cbase,
                        int* __restrict__ rptr, float* __restrict__ dinv,
                        int* __restrict__ cidx, int N, int E) {
    __shared__ int hist[CROWS];
    __shared__ int cur[CROWS];
    __shared__ int psum[256];
    int tid = threadIdx.x;
    int b = blockIdx.x;
    int lo = b * CROWS;
    int nr = min(CROWS, N - lo);
    int in0 = b * CAP;
    int cntE = min(ccur[b] - in0, CAP);
    int out0 = cbase[b];

    hist[tid] = 0; hist[tid + 256] = 0;
    __syncthreads();
    for (int i = tid; i < cntE; i += blockDim.x)
        atomicAdd(&hist[bkt[in0 + i] >> 17], 1);
    __syncthreads();
    // exclusive scan over 512: pair-sums -> 256-scan -> expand (deterministic)
    int h0 = hist[2 * tid], h1 = hist[2 * tid + 1];
    psum[tid] = h0 + h1;
    __syncthreads();
    #pragma unroll
    for (int off = 1; off < 256; off <<= 1) {
        int t = (tid >= off) ? psum[tid - off] : 0;
        __syncthreads();
        psum[tid] += t;
        __syncthreads();
    }
    int pex = psum[tid] - (h0 + h1);         // exclusive pair base
    cur[2 * tid]     = out0 + pex;
    cur[2 * tid + 1] = out0 + pex + h0;
    __syncthreads();
    // emit rptr + dinv for this bucket's rows
    for (int k = tid; k < nr; k += blockDim.x) {
        rptr[lo + k] = cur[k];
        dinv[lo + k] = rsqrtf((float)(hist[k] + 1));   // +1 self-loop
    }
    if (b == 0 && tid == 0) rptr[N] = E;
    __syncthreads();
    // place records into the contiguous window [out0, out0+cntE)
    for (int i = tid; i < cntE; i += blockDim.x) {
        int v = bkt[in0 + i];
        int p = atomicAdd(&cur[v >> 17], 1);
        cidx[p] = v & 0x1FFFF;
    }
}

// ---------------- MFMA GEMM: T[N,64] = H[N,64] @ W[64,64] ----------------
template <bool FP32IN>
__global__ void k_gemm(const void* __restrict__ Hv, const float* __restrict__ W,
                       ushort* __restrict__ T, int ntiles, int N) {
    int lane = threadIdx.x & 63;
    int wid = (blockIdx.x * blockDim.x + threadIdx.x) >> 6;
    int nw = (gridDim.x * blockDim.x) >> 6;
    int m = lane & 15, quad = lane >> 4;

    bfrag8 bf[2][4];   // all of W in B-frags, loaded once
    #pragma unroll
    for (int s = 0; s < 2; s++)
        #pragma unroll
        for (int c = 0; c < 4; c++) {
            bfrag8 f;
            #pragma unroll
            for (int j = 0; j < 8; j++) {
                int k = 32 * s + quad * 8 + j;
                f[j] = (short)f2bf(W[k * 64 + 16 * c + m]);
            }
            bf[s][c] = f;
        }

    for (int t = wid; t < ntiles; t += nw) {
        int nodeA = t * 16 + m;
        if (nodeA >= N) nodeA = N - 1;
        bfrag8 a0, a1;
        if (FP32IN) {
            const float* arow = (const float*)Hv + (size_t)nodeA * 64;
            #pragma unroll
            for (int s = 0; s < 2; s++) {
                float4 u0 = *(const float4*)(arow + s * 32 + quad * 8);
                float4 u1 = *(const float4*)(arow + s * 32 + quad * 8 + 4);
                bfrag8 f;
                f[0] = (short)f2bf(u0.x); f[1] = (short)f2bf(u0.y);
                f[2] = (short)f2bf(u0.z); f[3] = (short)f2bf(u0.w);
                f[4] = (short)f2bf(u1.x); f[5] = (short)f2bf(u1.y);
                f[6] = (short)f2bf(u1.z); f[7] = (short)f2bf(u1.w);
                if (s == 0) a0 = f; else a1 = f;
            }
        } else {
            const ushort* arow = (const ushort*)Hv + (size_t)nodeA * 64;
            a0 = *(const bfrag8*)(arow + quad * 8);
            a1 = *(const bfrag8*)(arow + 32 + quad * 8);
        }
        facc4 acc[4];
        #pragma unroll
        for (int c = 0; c < 4; c++) { acc[c][0]=0.f; acc[c][1]=0.f; acc[c][2]=0.f; acc[c][3]=0.f; }
        #pragma unroll
        for (int c = 0; c < 4; c++) {
            acc[c] = __builtin_amdgcn_mfma_f32_16x16x32_bf16(a0, bf[0][c], acc[c], 0, 0, 0);
            acc[c] = __builtin_amdgcn_mfma_f32_16x16x32_bf16(a1, bf[1][c], acc[c], 0, 0, 0);
        }
        #pragma unroll
        for (int c = 0; c < 4; c++)
            #pragma unroll
            for (int r = 0; r < 4; r++) {
                int node = t * 16 + quad * 4 + r;
                if (node < N) T[(size_t)node * 64 + c * 16 + m] = f2bf(acc[c][r]);
            }
    }
}

// ---------------- fused propagate + bias + BN + ReLU ----------------
__global__ void k_agg(const ushort* __restrict__ T, const int* __restrict__ rptr,
                      const float* __restrict__ dinv, const int* __restrict__ cidx,
                      const float* __restrict__ bias, const float* __restrict__ g,
                      const float* __restrict__ be, const float* __restrict__ mm,
                      const float* __restrict__ vv, int do_bn,
                      float* __restrict__ outf, ushort* __restrict__ outb, int N) {
    int lane = threadIdx.x & 63;
    int wid = (blockIdx.x * blockDim.x + threadIdx.x) >> 6;
    int nw = (gridDim.x * blockDim.x) >> 6;

    float bval = bias[lane];
    float sc = 1.f, sh = 0.f;
    if (do_bn) {
        sc = g[lane] * rsqrtf(vv[lane] + 1e-5f);
        sh = be[lane] - mm[lane] * sc;
    }

    for (int r = wid; r < N; r += nw) {
        int start = rptr[r];
        int e = rptr[r + 1] - start;
        float a0 = 0.f, a1 = 0.f, a2 = 0.f, a3 = 0.f;
        int i = 0;
        for (; i + 16 <= e; i += 16) {
            int cc[16];
            #pragma unroll
            for (int j = 0; j < 16; j++) cc[j] = cidx[start + i + j];
            float ww[16];
            #pragma unroll
            for (int j = 0; j < 16; j++) ww[j] = dinv[cc[j]];
            float tt[16];
            #pragma unroll
            for (int j = 0; j < 16; j++) tt[j] = bf2f(T[(size_t)cc[j] * 64 + lane]);
            #pragma unroll
            for (int j = 0; j < 16; j += 4) {
                a0 = fmaf(ww[j + 0], tt[j + 0], a0);
                a1 = fmaf(ww[j + 1], tt[j + 1], a1);
                a2 = fmaf(ww[j + 2], tt[j + 2], a2);
                a3 = fmaf(ww[j + 3], tt[j + 3], a3);
            }
        }
        for (; i + 4 <= e; i += 4) {
            int cc[4];
            #pragma unroll
            for (int j = 0; j < 4; j++) cc[j] = cidx[start + i + j];
            float ww[4];
            #pragma unroll
            for (int j = 0; j < 4; j++) ww[j] = dinv[cc[j]];
            float tt[4];
            #pragma unroll
            for (int j = 0; j < 4; j++) tt[j] = bf2f(T[(size_t)cc[j] * 64 + lane]);
            a0 = fmaf(ww[0], tt[0], a0);
            a1 = fmaf(ww[1], tt[1], a1);
            a2 = fmaf(ww[2], tt[2], a2);
            a3 = fmaf(ww[3], tt[3], a3);
        }
        for (; i < e; i++) {
            int c = cidx[start + i];
            a0 = fmaf(dinv[c], bf2f(T[(size_t)c * 64 + lane]), a0);
        }
        float dr = dinv[r];
        float val = dr * (((a0 + a1) + (a2 + a3)) + dr * bf2f(T[(size_t)r * 64 + lane])) + bval;
        if (do_bn) val = fmaxf(val * sc + sh, 0.f);
        if (outf) outf[(size_t)r * 64 + lane] = val;
        if (outb) outb[(size_t)r * 64 + lane] = f2bf(val);
    }
}

// ---------------- launcher ----------------

extern "C" void kernel_launch(void* const* d_in, const int* in_sizes, int n_in,
                              void* d_out, int out_size, void* d_ws, size_t ws_size,
                              hipStream_t stream) {
    const float* x  = (const float*)d_in[0];
    const int*   ei = (const int*)d_in[1];
    const float *W1 = (const float*)d_in[2],  *b1 = (const float*)d_in[3];
    const float *g1 = (const float*)d_in[4],  *be1= (const float*)d_in[5];
    const float *m1 = (const float*)d_in[6],  *v1 = (const float*)d_in[7];
    const float *W2 = (const float*)d_in[8],  *b2 = (const float*)d_in[9];
    const float *g2 = (const float*)d_in[10], *be2= (const float*)d_in[11];
    const float *m2 = (const float*)d_in[12], *v2 = (const float*)d_in[13];
    const float *W3 = (const float*)d_in[14], *b3 = (const float*)d_in[15];

    int N = in_sizes[0] / 64;
    int E = in_sizes[1] / 2;
    const int* row = ei;
    const int* col = ei + E;
    int ncb = (N + CROWS - 1) / CROWS;     // 196 for N=100K

    char* p = (char*)d_ws;
    auto take = [&](size_t b) -> char* {
        char* q = p;
        p += (b + 255) & ~(size_t)255;
        return q;
    };
    int*    ccur  = (int*)   take((size_t)ncb * 4);
    int*    cbase = (int*)   take((size_t)(ncb + 1) * 4);
    int*    rptr  = (int*)   take((size_t)(N + 1) * 4);
    float*  dinv  = (float*) take((size_t)N * 4);
    int*    bkt   = (int*)   take((size_t)ncb * CAP * 4);
    int*    cidx  = (int*)   take((size_t)E * 4);
    ushort* t     = (ushort*)take((size_t)N * 64 * 2);
    ushort* h     = (ushort*)take((size_t)N * 64 * 2);

    const int TB = 256;
    int nchunks = (E + CHUNK - 1) / CHUNK;
    k_cinit<<<(ncb + TB - 1) / TB, TB, 0, stream>>>(ccur, ncb);
    k_part <<<nchunks, TB, 0, stream>>>(row, col, E, ccur, bkt, ncb);
    k_scan <<<1, NCBMAX, 0, stream>>>(ccur, cbase, ncb);
    k_build<<<ncb, TB, 0, stream>>>(bkt, ccur, cbase, rptr, dinv, cidx, N, E);

    float* outp = (float*)d_out;   // [0, N*64): embeddings fp32; [N*64, 2N*64): preds
    int ntiles = (N + 15) >> 4;
    const int GG = 512;    // gemm blocks
    const int GA = 2048;   // agg blocks -> 8192 waves

    // layer 1 (fp32 x read directly, converted in-kernel)
    k_gemm<true> <<<GG, TB, 0, stream>>>(x, W1, t, ntiles, N);
    k_agg <<<GA, TB, 0, stream>>>(t, rptr, dinv, cidx, b1, g1, be1, m1, v1, 1,
                                  (float*)nullptr, h, N);
    // layer 2 -> embeddings (fp32 to d_out) + bf16 h for layer 3
    k_gemm<false><<<GG, TB, 0, stream>>>(h, W2, t, ntiles, N);
    k_agg <<<GA, TB, 0, stream>>>(t, rptr, dinv, cidx, b2, g2, be2, m2, v2, 1,
                                  outp, h, N);
    // layer 3 -> predictions
    k_gemm<false><<<GG, TB, 0, stream>>>(h, W3, t, ntiles, N);
    k_agg <<<GA, TB, 0, stream>>>(t, rptr, dinv, cidx, b3, b3, b3, b3, b3, 0,
                                  outp + (size_t)N * 64, (ushort*)nullptr, N);
}

// Round 8
// 331.666 us; speedup vs baseline: 2.1479x; 1.2916x over previous
//
#include <hip/hip_runtime.h>

typedef __attribute__((ext_vector_type(8))) short bfrag8;   // 8 bf16 in 4 VGPRs
typedef __attribute__((ext_vector_type(4))) float facc4;    // 4 fp32 acc

#define CROWS  512    // rows per coarse bucket (power of 2; rl fits 9 bits)
#define NCBMAX 256    // max coarse buckets (N <= 131072, also col 17-bit limit)
#define CAP    16384  // bkt region capacity per bucket (~2x expected load)
#define CHUNK  8192   // edges per k_part block

static __device__ __forceinline__ float bf2f(ushort u) {
    union { unsigned int i; float f; } x;
    x.i = ((unsigned int)u) << 16;
    return x.f;
}
static __device__ __forceinline__ ushort f2bf(float f) {
    union { float f; unsigned int i; } x;
    x.f = f;
    unsigned int r = x.i + 0x7FFFu + ((x.i >> 16) & 1u);   // RNE
    return (ushort)(r >> 16);
}

// ---------------- preprocessing: 2-phase partition, no global random atomics ----

__global__ void k_cinit(int* __restrict__ ccur, int ncb) {
    int b = blockIdx.x * blockDim.x + threadIdx.x;
    if (b < ncb) ccur[b] = b * CAP;
}

__global__ void k_part(const int* __restrict__ row, const int* __restrict__ col, int E,
                       int* __restrict__ ccur, int* __restrict__ bkt, int ncb) {
    __shared__ int recs[CHUNK];          // packed (rl<<17|col)
    __shared__ unsigned short cbl[CHUNK];
    __shared__ int hist[NCBMAX], lbase[NCBMAX], loff[NCBMAX];
    int tid = threadIdx.x;
    int chunk0 = blockIdx.x * CHUNK;
    for (int i = tid; i < ncb; i += blockDim.x) hist[i] = 0;
    __syncthreads();
    for (int j = tid; j < CHUNK; j += blockDim.x) {
        int e = chunk0 + j;
        if (e < E) {
            int r = row[e];
            int cb = r >> 9;
            recs[j] = ((r & (CROWS - 1)) << 17) | col[e];
            cbl[j] = (unsigned short)cb;
            atomicAdd(&hist[cb], 1);
        } else cbl[j] = 0xFFFF;
    }
    __syncthreads();
    for (int i = tid; i < ncb; i += blockDim.x) {
        int h = hist[i];
        lbase[i] = h ? atomicAdd(&ccur[i], h) : 0;
        loff[i] = 0;
    }
    __syncthreads();
    for (int j = tid; j < CHUNK; j += blockDim.x) {
        unsigned short cb = cbl[j];
        if (cb != 0xFFFF) {
            int p = lbase[cb] + atomicAdd(&loff[cb], 1);
            if (p < (cb + 1) * CAP) bkt[p] = recs[j];   // overflow guard (never hits)
        }
    }
}

__global__ void k_scan(const int* __restrict__ ccur, int* __restrict__ cbase, int ncb) {
    __shared__ int tmp[NCBMAX];
    int tid = threadIdx.x;
    int v = (tid < ncb) ? min(ccur[tid] - tid * CAP, CAP) : 0;
    tmp[tid] = v;
    __syncthreads();
    #pragma unroll
    for (int off = 1; off < NCBMAX; off <<= 1) {
        int t = (tid >= off) ? tmp[tid - off] : 0;
        __syncthreads();
        tmp[tid] += t;
        __syncthreads();
    }
    if (tid < ncb) cbase[tid] = tmp[tid] - v;   // exclusive
    if (tid == ncb - 1) cbase[ncb] = tmp[tid];
}

__global__ void k_build(const int* __restrict__ bkt, const int* __restrict__ ccur,
                        const int* __restrict__ cbase,
                        int* __restrict__ rptr, float* __restrict__ dinv,
                        int* __restrict__ cidx, int N, int E) {
    __shared__ int hist[CROWS];
    __shared__ int cur[CROWS];
    __shared__ int psum[256];
    int tid = threadIdx.x;
    int b = blockIdx.x;
    int lo = b * CROWS;
    int nr = min(CROWS, N - lo);
    int in0 = b * CAP;
    int cntE = min(ccur[b] - in0, CAP);
    int out0 = cbase[b];

    hist[tid] = 0; hist[tid + 256] = 0;
    __syncthreads();
    for (int i = tid; i < cntE; i += blockDim.x)
        atomicAdd(&hist[bkt[in0 + i] >> 17], 1);
    __syncthreads();
    int h0 = hist[2 * tid], h1 = hist[2 * tid + 1];
    psum[tid] = h0 + h1;
    __syncthreads();
    #pragma unroll
    for (int off = 1; off < 256; off <<= 1) {
        int t = (tid >= off) ? psum[tid - off] : 0;
        __syncthreads();
        psum[tid] += t;
        __syncthreads();
    }
    int pex = psum[tid] - (h0 + h1);
    cur[2 * tid]     = out0 + pex;
    cur[2 * tid + 1] = out0 + pex + h0;
    __syncthreads();
    for (int k = tid; k < nr; k += blockDim.x) {
        rptr[lo + k] = cur[k];
        dinv[lo + k] = rsqrtf((float)(hist[k] + 1));   // +1 self-loop
    }
    if (b == 0 && tid == 0) rptr[N] = E;
    __syncthreads();
    for (int i = tid; i < cntE; i += blockDim.x) {
        int v = bkt[in0 + i];
        int p = atomicAdd(&cur[v >> 17], 1);
        cidx[p] = v & 0x1FFFF;
    }
}

// ---------------- MFMA GEMM: T2[N,64] = dinv[n] * (H[N,64] @ W[64,64]) ----------------
template <bool FP32IN>
__global__ void k_gemm(const void* __restrict__ Hv, const float* __restrict__ W,
                       const float* __restrict__ dinv,
                       ushort* __restrict__ T, int ntiles, int N) {
    int lane = threadIdx.x & 63;
    int wid = (blockIdx.x * blockDim.x + threadIdx.x) >> 6;
    int nw = (gridDim.x * blockDim.x) >> 6;
    int m = lane & 15, quad = lane >> 4;

    bfrag8 bf[2][4];   // all of W in B-frags, loaded once
    #pragma unroll
    for (int s = 0; s < 2; s++)
        #pragma unroll
        for (int c = 0; c < 4; c++) {
            bfrag8 f;
            #pragma unroll
            for (int j = 0; j < 8; j++) {
                int k = 32 * s + quad * 8 + j;
                f[j] = (short)f2bf(W[k * 64 + 16 * c + m]);
            }
            bf[s][c] = f;
        }

    for (int t = wid; t < ntiles; t += nw) {
        int nodeA = t * 16 + m;
        if (nodeA >= N) nodeA = N - 1;
        bfrag8 a0, a1;
        if (FP32IN) {
            const float* arow = (const float*)Hv + (size_t)nodeA * 64;
            #pragma unroll
            for (int s = 0; s < 2; s++) {
                float4 u0 = *(const float4*)(arow + s * 32 + quad * 8);
                float4 u1 = *(const float4*)(arow + s * 32 + quad * 8 + 4);
                bfrag8 f;
                f[0] = (short)f2bf(u0.x); f[1] = (short)f2bf(u0.y);
                f[2] = (short)f2bf(u0.z); f[3] = (short)f2bf(u0.w);
                f[4] = (short)f2bf(u1.x); f[5] = (short)f2bf(u1.y);
                f[6] = (short)f2bf(u1.z); f[7] = (short)f2bf(u1.w);
                if (s == 0) a0 = f; else a1 = f;
            }
        } else {
            const ushort* arow = (const ushort*)Hv + (size_t)nodeA * 64;
            a0 = *(const bfrag8*)(arow + quad * 8);
            a1 = *(const bfrag8*)(arow + 32 + quad * 8);
        }
        facc4 acc[4];
        #pragma unroll
        for (int c = 0; c < 4; c++) { acc[c][0]=0.f; acc[c][1]=0.f; acc[c][2]=0.f; acc[c][3]=0.f; }
        #pragma unroll
        for (int c = 0; c < 4; c++) {
            acc[c] = __builtin_amdgcn_mfma_f32_16x16x32_bf16(a0, bf[0][c], acc[c], 0, 0, 0);
            acc[c] = __builtin_amdgcn_mfma_f32_16x16x32_bf16(a1, bf[1][c], acc[c], 0, 0, 0);
        }
        #pragma unroll
        for (int c = 0; c < 4; c++)
            #pragma unroll
            for (int r = 0; r < 4; r++) {
                int node = t * 16 + quad * 4 + r;
                if (node < N)
                    T[(size_t)node * 64 + c * 16 + m] = f2bf(dinv[node] * acc[c][r]);
            }
    }
}

// ---------------- fused propagate + bias + BN + ReLU ----------------
// T2 rows are pre-scaled by dinv[c]:  out[r] = dinv[r]*(sum_e T2[c_e] + T2[r]) + b
// 4 rows per wave (16 lanes x ushort4 each): one gather instr = 4 edges (512B in
// flight), 16-deep unroll = 64 edges in flight per wave.
__global__ void k_agg(const ushort* __restrict__ T2, const int* __restrict__ rptr,
                      const float* __restrict__ dinv, const int* __restrict__ cidx,
                      const float* __restrict__ bias, const float* __restrict__ g,
                      const float* __restrict__ be, const float* __restrict__ mm,
                      const float* __restrict__ vv, int do_bn,
                      float* __restrict__ outf, ushort* __restrict__ outb, int N) {
    int lane = threadIdx.x & 63;
    int wid = (blockIdx.x * blockDim.x + threadIdx.x) >> 6;
    int nw = (gridDim.x * blockDim.x) >> 6;
    int grp = lane >> 4;       // which of the 4 rows this lane serves
    int s   = lane & 15;       // sub-lane: channels s*4 .. s*4+3

    // per-channel constants (4 channels per lane)
    float4 b4 = *(const float4*)(bias + s * 4);
    float4 sc4 = make_float4(1.f, 1.f, 1.f, 1.f);
    float4 sh4 = make_float4(0.f, 0.f, 0.f, 0.f);
    if (do_bn) {
        float4 g4 = *(const float4*)(g + s * 4);
        float4 v4 = *(const float4*)(vv + s * 4);
        float4 m4 = *(const float4*)(mm + s * 4);
        float4 e4 = *(const float4*)(be + s * 4);
        sc4.x = g4.x * rsqrtf(v4.x + 1e-5f); sh4.x = e4.x - m4.x * sc4.x;
        sc4.y = g4.y * rsqrtf(v4.y + 1e-5f); sh4.y = e4.y - m4.y * sc4.y;
        sc4.z = g4.z * rsqrtf(v4.z + 1e-5f); sh4.z = e4.z - m4.z * sc4.z;
        sc4.w = g4.w * rsqrtf(v4.w + 1e-5f); sh4.w = e4.w - m4.w * sc4.w;
    }

    int nquads = (N + 3) >> 2;
    for (int q = wid; q < nquads; q += nw) {
        int r = q * 4 + grp;
        bool rv = (r < N);
        int start = rv ? rptr[r] : 0;
        int e = rv ? (rptr[r + 1] - start) : 0;
        float a0 = 0.f, a1 = 0.f, a2 = 0.f, a3 = 0.f;
        for (int i = 0; i < e; i += 16) {
            int c[16];
            #pragma unroll
            for (int j = 0; j < 16; j++)
                c[j] = cidx[start + min(i + j, e - 1)];   // group-broadcast load
            ushort4 t4[16];
            #pragma unroll
            for (int j = 0; j < 16; j++)
                t4[j] = *(const ushort4*)(T2 + (size_t)c[j] * 64 + s * 4);
            #pragma unroll
            for (int j = 0; j < 16; j++) {
                float mj = (i + j < e) ? 1.f : 0.f;
                a0 = fmaf(mj, bf2f(t4[j].x), a0);
                a1 = fmaf(mj, bf2f(t4[j].y), a1);
                a2 = fmaf(mj, bf2f(t4[j].z), a2);
                a3 = fmaf(mj, bf2f(t4[j].w), a3);
            }
        }
        if (rv) {
            ushort4 self4 = *(const ushort4*)(T2 + (size_t)r * 64 + s * 4);
            float dr = dinv[r];
            float v0 = dr * (a0 + bf2f(self4.x)) + b4.x;
            float v1 = dr * (a1 + bf2f(self4.y)) + b4.y;
            float v2 = dr * (a2 + bf2f(self4.z)) + b4.z;
            float v3 = dr * (a3 + bf2f(self4.w)) + b4.w;
            if (do_bn) {
                v0 = fmaxf(v0 * sc4.x + sh4.x, 0.f);
                v1 = fmaxf(v1 * sc4.y + sh4.y, 0.f);
                v2 = fmaxf(v2 * sc4.z + sh4.z, 0.f);
                v3 = fmaxf(v3 * sc4.w + sh4.w, 0.f);
            }
            if (outf) *(float4*)(outf + (size_t)r * 64 + s * 4) = make_float4(v0, v1, v2, v3);
            if (outb) {
                ushort4 o;
                o.x = f2bf(v0); o.y = f2bf(v1); o.z = f2bf(v2); o.w = f2bf(v3);
                *(ushort4*)(outb + (size_t)r * 64 + s * 4) = o;
            }
        }
    }
}

// ---------------- launcher ----------------

extern "C" void kernel_launch(void* const* d_in, const int* in_sizes, int n_in,
                              void* d_out, int out_size, void* d_ws, size_t ws_size,
                              hipStream_t stream) {
    const float* x  = (const float*)d_in[0];
    const int*   ei = (const int*)d_in[1];
    const float *W1 = (const float*)d_in[2],  *b1 = (const float*)d_in[3];
    const float *g1 = (const float*)d_in[4],  *be1= (const float*)d_in[5];
    const float *m1 = (const float*)d_in[6],  *v1 = (const float*)d_in[7];
    const float *W2 = (const float*)d_in[8],  *b2 = (const float*)d_in[9];
    const float *g2 = (const float*)d_in[10], *be2= (const float*)d_in[11];
    const float *m2 = (const float*)d_in[12], *v2 = (const float*)d_in[13];
    const float *W3 = (const float*)d_in[14], *b3 = (const float*)d_in[15];

    int N = in_sizes[0] / 64;
    int E = in_sizes[1] / 2;
    const int* row = ei;
    const int* col = ei + E;
    int ncb = (N + CROWS - 1) / CROWS;

    char* p = (char*)d_ws;
    auto take = [&](size_t b) -> char* {
        char* q = p;
        p += (b + 255) & ~(size_t)255;
        return q;
    };
    int*    ccur  = (int*)   take((size_t)ncb * 4);
    int*    cbase = (int*)   take((size_t)(ncb + 1) * 4);
    int*    rptr  = (int*)   take((size_t)(N + 1) * 4);
    float*  dinv  = (float*) take((size_t)N * 4);
    int*    bkt   = (int*)   take((size_t)ncb * CAP * 4);
    int*    cidx  = (int*)   take((size_t)E * 4);
    ushort* t     = (ushort*)take((size_t)N * 64 * 2);
    ushort* h     = (ushort*)take((size_t)N * 64 * 2);

    const int TB = 256;
    int nchunks = (E + CHUNK - 1) / CHUNK;
    k_cinit<<<(ncb + TB - 1) / TB, TB, 0, stream>>>(ccur, ncb);
    k_part <<<nchunks, TB, 0, stream>>>(row, col, E, ccur, bkt, ncb);
    k_scan <<<1, NCBMAX, 0, stream>>>(ccur, cbase, ncb);
    k_build<<<ncb, TB, 0, stream>>>(bkt, ccur, cbase, rptr, dinv, cidx, N, E);

    float* outp = (float*)d_out;   // [0, N*64): embeddings fp32; [N*64, 2N*64): preds
    int ntiles = (N + 15) >> 4;
    const int GG = 1024;   // gemm blocks
    const int GA = 2048;   // agg blocks -> 8192 waves (4 rows each)

    // layer 1 (fp32 x read directly, converted in-kernel)
    k_gemm<true> <<<GG, TB, 0, stream>>>(x, W1, dinv, t, ntiles, N);
    k_agg <<<GA, TB, 0, stream>>>(t, rptr, dinv, cidx, b1, g1, be1, m1, v1, 1,
                                  (float*)nullptr, h, N);
    // layer 2 -> embeddings (fp32 to d_out) + bf16 h for layer 3
    k_gemm<false><<<GG, TB, 0, stream>>>(h, W2, dinv, t, ntiles, N);
    k_agg <<<GA, TB, 0, stream>>>(t, rptr, dinv, cidx, b2, g2, be2, m2, v2, 1,
                                  outp, h, N);
    // layer 3 -> predictions
    k_gemm<false><<<GG, TB, 0, stream>>>(h, W3, dinv, t, ntiles, N);
    k_agg <<<GA, TB, 0, stream>>>(t, rptr, dinv, cidx, b3, b3, b3, b3, b3, 0,
                                  outp + (size_t)N * 64, (ushort*)nullptr, N);
}

// Round 9
// 293.934 us; speedup vs baseline: 2.4236x; 1.1284x over previous
//
#include <hip/hip_runtime.h>

typedef __attribute__((ext_vector_type(8))) short bfrag8;          // 8 bf16 in 4 VGPRs
typedef __attribute__((ext_vector_type(4))) float facc4;           // 4 fp32 acc
typedef __attribute__((ext_vector_type(8))) unsigned short u16x8;  // 16B lane load

#define CROWS  256    // rows per coarse bucket (rl fits 8 bits)
#define NCBMAX 512    // max coarse buckets (N <= 131072; col fits 17 bits)
#define CAP    8192   // bkt region capacity per bucket (~2x expected 4081)
#define CHUNK  4096   // edges per k_part block
#define SLACK  772    // per-bucket cidx padding slack (256 rows * 3 + align)

static __device__ __forceinline__ float bf2f(ushort u) {
    union { unsigned int i; float f; } x;
    x.i = ((unsigned int)u) << 16;
    return x.f;
}
static __device__ __forceinline__ ushort f2bf(float f) {
    union { float f; unsigned int i; } x;
    x.f = f;
    unsigned int r = x.i + 0x7FFFu + ((x.i >> 16) & 1u);   // RNE
    return (ushort)(r >> 16);
}

// ---------------- preprocessing: 2-phase partition, no global random atomics ----

// init bucket cursors + zero the sentinel row T2[N] (gathers of padding hit it)
__global__ void k_cinit(int* __restrict__ ccur, int ncb, ushort* __restrict__ t, int N) {
    int b = blockIdx.x * blockDim.x + threadIdx.x;
    if (b < ncb) ccur[b] = b * CAP;
    if (blockIdx.x == 0 && threadIdx.x < 64) t[(size_t)N * 64 + threadIdx.x] = 0;
}

__global__ void k_part(const int* __restrict__ row, const int* __restrict__ col, int E,
                       int* __restrict__ ccur, int* __restrict__ bkt, int ncb) {
    __shared__ int recs[CHUNK];          // packed (rl<<17|col)
    __shared__ unsigned short cbl[CHUNK];
    __shared__ int hist[NCBMAX], lbase[NCBMAX], loff[NCBMAX];
    int tid = threadIdx.x;
    int chunk0 = blockIdx.x * CHUNK;
    for (int i = tid; i < ncb; i += blockDim.x) hist[i] = 0;
    __syncthreads();
    for (int j = tid; j < CHUNK; j += blockDim.x) {
        int e = chunk0 + j;
        if (e < E) {
            int r = row[e];
            int cb = r >> 8;
            recs[j] = ((r & (CROWS - 1)) << 17) | col[e];
            cbl[j] = (unsigned short)cb;
            atomicAdd(&hist[cb], 1);
        } else cbl[j] = 0xFFFF;
    }
    __syncthreads();
    for (int i = tid; i < ncb; i += blockDim.x) {
        int h = hist[i];
        lbase[i] = h ? atomicAdd(&ccur[i], h) : 0;
        loff[i] = 0;
    }
    __syncthreads();
    for (int j = tid; j < CHUNK; j += blockDim.x) {
        unsigned short cb = cbl[j];
        if (cb != 0xFFFF) {
            int p = lbase[cb] + atomicAdd(&loff[cb], 1);
            if (p < (cb + 1) * CAP) bkt[p] = recs[j];   // overflow guard (never hits)
        }
    }
}

__global__ void k_scan(const int* __restrict__ ccur, int* __restrict__ cbase, int ncb) {
    __shared__ int tmp[NCBMAX];
    int tid = threadIdx.x;
    int v = (tid < ncb) ? min(ccur[tid] - tid * CAP, CAP) : 0;
    tmp[tid] = v;
    __syncthreads();
    #pragma unroll
    for (int off = 1; off < NCBMAX; off <<= 1) {
        int t = (tid >= off) ? tmp[tid - off] : 0;
        __syncthreads();
        tmp[tid] += t;
        __syncthreads();
    }
    if (tid < ncb) cbase[tid] = tmp[tid] - v;   // exclusive
    if (tid == ncb - 1) cbase[ncb] = tmp[tid];
}

// per bucket: row hist -> deg/dinv, padded-window scan -> rptr (4-aligned),
// LDS-cursor placement, sentinel fill. Zero global atomics.
__global__ void k_build(const int* __restrict__ bkt, const int* __restrict__ ccur,
                        const int* __restrict__ cbase,
                        int* __restrict__ rptr, int* __restrict__ deg,
                        float* __restrict__ dinv, int* __restrict__ cidx, int N) {
    __shared__ int hist[CROWS], wstart[CROWS], cur[CROWS], psum[CROWS];
    int tid = threadIdx.x;
    int b = blockIdx.x;
    int lo = b * CROWS;
    int nr = min(CROWS, N - lo);
    int in0 = b * CAP;
    int cntE = min(ccur[b] - in0, CAP);
    int out0 = ((cbase[b] + 3) & ~3) + b * SLACK;   // 16B-aligned bucket base

    hist[tid] = 0;
    __syncthreads();
    for (int i = tid; i < cntE; i += blockDim.x)
        atomicAdd(&hist[bkt[in0 + i] >> 17], 1);
    __syncthreads();
    int d = hist[tid];
    int ep = (d + 3) & ~3;                  // padded row length (multiple of 4)
    psum[tid] = ep;
    __syncthreads();
    #pragma unroll
    for (int off = 1; off < CROWS; off <<= 1) {
        int t = (tid >= off) ? psum[tid - off] : 0;
        __syncthreads();
        psum[tid] += t;
        __syncthreads();
    }
    int ws = out0 + psum[tid] - ep;
    wstart[tid] = ws;
    cur[tid] = ws;
    if (tid < nr) {
        rptr[lo + tid] = ws;
        deg[lo + tid] = d;
        dinv[lo + tid] = rsqrtf((float)(d + 1));   // +1 self-loop
    }
    __syncthreads();
    for (int i = tid; i < cntE; i += blockDim.x) {
        int v = bkt[in0 + i];
        int p = atomicAdd(&cur[v >> 17], 1);
        cidx[p] = v & 0x1FFFF;
    }
    __syncthreads();
    if (tid < nr)
        for (int j = d; j < ep; j++) cidx[wstart[tid] + j] = N;   // sentinels
}

// ---------------- MFMA GEMM: T2[N,64] = dinv[n] * (H[N,64] @ W[64,64]) ----------------
template <bool FP32IN>
__global__ void k_gemm(const void* __restrict__ Hv, const float* __restrict__ W,
                       const float* __restrict__ dinv,
                       ushort* __restrict__ T, int ntiles, int N) {
    int lane = threadIdx.x & 63;
    int wid = (blockIdx.x * blockDim.x + threadIdx.x) >> 6;
    int nw = (gridDim.x * blockDim.x) >> 6;
    int m = lane & 15, quad = lane >> 4;

    bfrag8 bf[2][4];   // all of W in B-frags, loaded once
    #pragma unroll
    for (int s = 0; s < 2; s++)
        #pragma unroll
        for (int c = 0; c < 4; c++) {
            bfrag8 f;
            #pragma unroll
            for (int j = 0; j < 8; j++) {
                int k = 32 * s + quad * 8 + j;
                f[j] = (short)f2bf(W[k * 64 + 16 * c + m]);
            }
            bf[s][c] = f;
        }

    for (int t = wid; t < ntiles; t += nw) {
        int nodeA = t * 16 + m;
        if (nodeA >= N) nodeA = N - 1;
        bfrag8 a0, a1;
        if (FP32IN) {
            const float* arow = (const float*)Hv + (size_t)nodeA * 64;
            #pragma unroll
            for (int s = 0; s < 2; s++) {
                float4 u0 = *(const float4*)(arow + s * 32 + quad * 8);
                float4 u1 = *(const float4*)(arow + s * 32 + quad * 8 + 4);
                bfrag8 f;
                f[0] = (short)f2bf(u0.x); f[1] = (short)f2bf(u0.y);
                f[2] = (short)f2bf(u0.z); f[3] = (short)f2bf(u0.w);
                f[4] = (short)f2bf(u1.x); f[5] = (short)f2bf(u1.y);
                f[6] = (short)f2bf(u1.z); f[7] = (short)f2bf(u1.w);
                if (s == 0) a0 = f; else a1 = f;
            }
        } else {
            const ushort* arow = (const ushort*)Hv + (size_t)nodeA * 64;
            a0 = *(const bfrag8*)(arow + quad * 8);
            a1 = *(const bfrag8*)(arow + 32 + quad * 8);
        }
        facc4 acc[4];
        #pragma unroll
        for (int c = 0; c < 4; c++) { acc[c][0]=0.f; acc[c][1]=0.f; acc[c][2]=0.f; acc[c][3]=0.f; }
        #pragma unroll
        for (int c = 0; c < 4; c++) {
            acc[c] = __builtin_amdgcn_mfma_f32_16x16x32_bf16(a0, bf[0][c], acc[c], 0, 0, 0);
            acc[c] = __builtin_amdgcn_mfma_f32_16x16x32_bf16(a1, bf[1][c], acc[c], 0, 0, 0);
        }
        #pragma unroll
        for (int c = 0; c < 4; c++)
            #pragma unroll
            for (int r = 0; r < 4; r++) {
                int node = t * 16 + quad * 4 + r;
                if (node < N)
                    T[(size_t)node * 64 + c * 16 + m] = f2bf(dinv[node] * acc[c][r]);
            }
    }
}

// ---------------- fused propagate + bias + BN + ReLU ----------------
// T2 pre-scaled by dinv[c]; rows padded to x4 with sentinel->zero-row:
// mask-free inner loop. 8 rows/wave, 8 lanes/row, ushort8 (16B) per lane.
__global__ void k_agg(const ushort* __restrict__ T2, const int* __restrict__ rptr,
                      const int* __restrict__ deg, const float* __restrict__ dinv,
                      const int* __restrict__ cidx,
                      const float* __restrict__ bias, const float* __restrict__ g,
                      const float* __restrict__ be, const float* __restrict__ mm,
                      const float* __restrict__ vv, int do_bn,
                      float* __restrict__ outf, ushort* __restrict__ outb, int N) {
    int lane = threadIdx.x & 63;
    int wid = (blockIdx.x * blockDim.x + threadIdx.x) >> 6;
    int nw = (gridDim.x * blockDim.x) >> 6;
    int grp = lane >> 3;      // which of 8 rows
    int s = lane & 7;         // channel slice: s*8 .. s*8+7

    float bb[8], sc[8], sh[8];
    #pragma unroll
    for (int k = 0; k < 8; k++) { bb[k] = bias[s * 8 + k]; sc[k] = 1.f; sh[k] = 0.f; }
    if (do_bn) {
        #pragma unroll
        for (int k = 0; k < 8; k++) {
            sc[k] = g[s * 8 + k] * rsqrtf(vv[s * 8 + k] + 1e-5f);
            sh[k] = be[s * 8 + k] - mm[s * 8 + k] * sc[k];
        }
    }

    int noct = (N + 7) >> 3;
    for (int q = wid; q < noct; q += nw) {
        int r = q * 8 + grp;
        bool rv = (r < N);
        int start = rv ? rptr[r] : 0;
        int ep = rv ? ((deg[r] + 3) & ~3) : 0;
        float a[8];
        #pragma unroll
        for (int k = 0; k < 8; k++) a[k] = 0.f;
        for (int i = 0; i < ep; i += 4) {
            int4 c4 = *(const int4*)(cidx + start + i);       // 1 load = 4 edges
            u16x8 t0 = *(const u16x8*)(T2 + (size_t)c4.x * 64 + s * 8);
            u16x8 t1 = *(const u16x8*)(T2 + (size_t)c4.y * 64 + s * 8);
            u16x8 t2 = *(const u16x8*)(T2 + (size_t)c4.z * 64 + s * 8);
            u16x8 t3 = *(const u16x8*)(T2 + (size_t)c4.w * 64 + s * 8);
            #pragma unroll
            for (int k = 0; k < 8; k++)
                a[k] += (bf2f(t0[k]) + bf2f(t1[k])) + (bf2f(t2[k]) + bf2f(t3[k]));
        }
        if (rv) {
            u16x8 sf = *(const u16x8*)(T2 + (size_t)r * 64 + s * 8);
            float dr = dinv[r];
            float v[8];
            #pragma unroll
            for (int k = 0; k < 8; k++) {
                v[k] = dr * (a[k] + bf2f(sf[k])) + bb[k];
                if (do_bn) v[k] = fmaxf(v[k] * sc[k] + sh[k], 0.f);
            }
            if (outf) {
                *(float4*)(outf + (size_t)r * 64 + s * 8) = make_float4(v[0], v[1], v[2], v[3]);
                *(float4*)(outf + (size_t)r * 64 + s * 8 + 4) = make_float4(v[4], v[5], v[6], v[7]);
            }
            if (outb) {
                u16x8 o;
                #pragma unroll
                for (int k = 0; k < 8; k++) o[k] = f2bf(v[k]);
                *(u16x8*)(outb + (size_t)r * 64 + s * 8) = o;
            }
        }
    }
}

// ---------------- launcher ----------------

extern "C" void kernel_launch(void* const* d_in, const int* in_sizes, int n_in,
                              void* d_out, int out_size, void* d_ws, size_t ws_size,
                              hipStream_t stream) {
    const float* x  = (const float*)d_in[0];
    const int*   ei = (const int*)d_in[1];
    const float *W1 = (const float*)d_in[2],  *b1 = (const float*)d_in[3];
    const float *g1 = (const float*)d_in[4],  *be1= (const float*)d_in[5];
    const float *m1 = (const float*)d_in[6],  *v1 = (const float*)d_in[7];
    const float *W2 = (const float*)d_in[8],  *b2 = (const float*)d_in[9];
    const float *g2 = (const float*)d_in[10], *be2= (const float*)d_in[11];
    const float *m2 = (const float*)d_in[12], *v2 = (const float*)d_in[13];
    const float *W3 = (const float*)d_in[14], *b3 = (const float*)d_in[15];

    int N = in_sizes[0] / 64;
    int E = in_sizes[1] / 2;
    const int* row = ei;
    const int* col = ei + E;
    int ncb = (N + CROWS - 1) / CROWS;

    char* p = (char*)d_ws;
    auto take = [&](size_t b) -> char* {
        char* q = p;
        p += (b + 255) & ~(size_t)255;
        return q;
    };
    int*    ccur  = (int*)   take((size_t)ncb * 4);
    int*    cbase = (int*)   take((size_t)(ncb + 1) * 4);
    int*    rptr  = (int*)   take((size_t)N * 4);
    int*    deg   = (int*)   take((size_t)N * 4);
    float*  dinv  = (float*) take((size_t)N * 4);
    int*    bkt   = (int*)   take((size_t)ncb * CAP * 4);
    int*    cidx  = (int*)   take((size_t)(E + ncb * SLACK + 64) * 4);
    ushort* t     = (ushort*)take((size_t)(N + 1) * 64 * 2);   // +1 sentinel row
    ushort* h     = (ushort*)take((size_t)N * 64 * 2);

    const int TB = 256;
    int nchunks = (E + CHUNK - 1) / CHUNK;
    k_cinit<<<(ncb + TB - 1) / TB, TB, 0, stream>>>(ccur, ncb, t, N);
    k_part <<<nchunks, TB, 0, stream>>>(row, col, E, ccur, bkt, ncb);
    k_scan <<<1, NCBMAX, 0, stream>>>(ccur, cbase, ncb);
    k_build<<<ncb, TB, 0, stream>>>(bkt, ccur, cbase, rptr, deg, dinv, cidx, N);

    float* outp = (float*)d_out;   // [0, N*64): embeddings fp32; [N*64, 2N*64): preds
    int ntiles = (N + 15) >> 4;
    const int GG = 1024;                       // gemm blocks
    int noct = (N + 7) >> 3;
    int GA = (noct + 3) / 4;                   // one row-octet per wave

    // layer 1 (fp32 x read directly, converted in-kernel)
    k_gemm<true> <<<GG, TB, 0, stream>>>(x, W1, dinv, t, ntiles, N);
    k_agg <<<GA, TB, 0, stream>>>(t, rptr, deg, dinv, cidx, b1, g1, be1, m1, v1, 1,
                                  (float*)nullptr, h, N);
    // layer 2 -> embeddings (fp32 to d_out) + bf16 h for layer 3
    k_gemm<false><<<GG, TB, 0, stream>>>(h, W2, dinv, t, ntiles, N);
    k_agg <<<GA, TB, 0, stream>>>(t, rptr, deg, dinv, cidx, b2, g2, be2, m2, v2, 1,
                                  outp, h, N);
    // layer 3 -> predictions
    k_gemm<false><<<GG, TB, 0, stream>>>(h, W3, dinv, t, ntiles, N);
    k_agg <<<GA, TB, 0, stream>>>(t, rptr, deg, dinv, cidx, b3, b3, b3, b3, b3, 0,
                                  outp + (size_t)N * 64, (ushort*)nullptr, N);
}